// Round 8
// baseline (60.451 us; speedup 1.0000x reference)
//
#include <hip/hip_runtime.h>

// x[64][16][8192] f32, J=4, LEVELS=13, eps 1e-5.
// targets[j] = blockmean(2^(13-j)); inputs[j] = BN(blockmean(2^(13-j)) - blockmean(2^(14-j))), input[0]=BN(m0)
// Output [2][4][64][16][8192] f32.
// K1: per row: reduce x-row -> 15 block-mean stats + 4 BN second-moment contributions.
// K2: 512 blocks, each writes ONE contiguous 512KB region [part][j][b][*][*]
//     (long linear store streams, mimicking fillBuffer's access topology).

#define SSTR 16
// stats row: [0]=m0, [1..2]=m1, [3..6]=m2, [7..14]=m3  (level j at base (1<<j)-1, count 1<<j)

typedef float f32x4 __attribute__((ext_vector_type(4)));

__global__ __launch_bounds__(256) void row_stats_kernel(const float* __restrict__ x,
                                                        float* __restrict__ stats,
                                                        float* __restrict__ mom) {
    int row = blockIdx.x;                 // 0..1023  (b=row>>4, c=row&15)
    int t = threadIdx.x;
    int lane = t & 63, wave = t >> 6;
    const f32x4* xr = reinterpret_cast<const f32x4*>(x) + (size_t)row * 2048;
    float s[8];
#pragma unroll
    for (int k = 0; k < 8; ++k) {
        f32x4 v = xr[t + 256 * k];        // iter k = 1024-block k
        s[k] = (v.x + v.y) + (v.z + v.w);
    }
    __shared__ float red[8][4];
    __shared__ float sb[16];
#pragma unroll
    for (int k = 0; k < 8; ++k) {
        float v = s[k];
#pragma unroll
        for (int off = 32; off; off >>= 1) v += __shfl_down(v, off, 64);
        if (lane == 0) red[k][wave] = v;
    }
    __syncthreads();
    if (t < 8) sb[7 + t] = (red[t][0] + red[t][1] + red[t][2] + red[t][3]) * (1.0f / 1024.0f);
    __syncthreads();
    if (t == 0) {
        float m2[4], m1[2];
#pragma unroll
        for (int k = 0; k < 4; ++k) m2[k] = 0.5f * (sb[7 + 2 * k] + sb[8 + 2 * k]);
        m1[0] = 0.5f * (m2[0] + m2[1]);
        m1[1] = 0.5f * (m2[2] + m2[3]);
        sb[0] = 0.5f * (m1[0] + m1[1]);
        sb[1] = m1[0]; sb[2] = m1[1];
        sb[3] = m2[0]; sb[4] = m2[1]; sb[5] = m2[2]; sb[6] = m2[3];
    }
    __syncthreads();
    if (t < 15) stats[(size_t)row * SSTR + t] = sb[t];
    if (t < 4) {                          // j = t: second-moment contribution of this row
        int j = t, nb = 1 << j;
        float acc;
        if (j == 0) {
            acc = sb[0] * sb[0];
        } else {
            int base = nb - 1, pb = (nb >> 1) - 1;
            acc = 0.f;
            for (int k = 0; k < nb; ++k) {
                float d = sb[base + k] - sb[pb + (k >> 1)];
                acc += d * d;
            }
        }
        mom[(size_t)row * 4 + j] = acc * (float)(8192 >> j);
    }
}

template <int JJ>
__device__ inline void store_region(const float* __restrict__ val, f32x4* __restrict__ ob, int t) {
#pragma unroll
    for (int i = 0; i < 128; ++i) {       // 128 x 4KB contiguous steps = 512KB linear
        int c = i >> 3;
        int run = (i & 7) >> (3 - JJ);    // compile-time per i
        float v = val[c * 8 + run];       // uniform LDS broadcast
        f32x4 q = {v, v, v, v};
        ob[i * 256 + t] = q;
    }
}

__global__ __launch_bounds__(256) void write_all_kernel(const float* __restrict__ stats,
                                                        const float* __restrict__ mom,
                                                        const float* __restrict__ gamma,
                                                        const float* __restrict__ beta,
                                                        f32x4* __restrict__ out) {
    int blk = blockIdx.x;                 // 0..511 = [part][j][b]
    int part = blk >> 8;
    int j = (blk >> 6) & 3;
    int b = blk & 63;
    int t = threadIdx.x;
    int lane = t & 63, wave = t >> 6;
    int nb = 1 << j;

    __shared__ float sc[16], sh[16];
    __shared__ float val[128];            // [c][run]

    if (part == 0) {                      // BN coeffs for (j, all c); wave w -> channels 4w..4w+3
#pragma unroll
        for (int q = 0; q < 4; ++q) {
            int c = wave * 4 + q;
            float m = mom[((size_t)(lane << 4) + c) * 4 + j];
            float mu = (j == 0) ? stats[((size_t)(lane << 4) + c) * SSTR] : 0.f;
#pragma unroll
            for (int off = 32; off; off >>= 1) {
                m  += __shfl_down(m, off, 64);
                mu += __shfl_down(mu, off, 64);
            }
            if (lane == 0) {
                const float N = 64.0f * 8192.0f;
                float mean = mu * (1.0f / 64.0f);   // exactly 0 for j>=1 (mu==0)
                float var = m / N - mean * mean;
                float s_ = gamma[(j << 4) + c] * rsqrtf(var + 1e-5f);
                sc[c] = s_;
                sh[c] = beta[(j << 4) + c] - mean * s_;
            }
        }
    }
    __syncthreads();
    if (t < 128) {                        // fill run-value table for this (part,j,b)
        int c = t >> 3, run = t & 7;
        int rr = run & (nb - 1);
        const float* sp = stats + ((size_t)(b << 4) + c) * SSTR;
        float m = sp[nb - 1 + rr];
        float v;
        if (part) {
            v = m;
        } else {
            float d = (j == 0) ? m : m - sp[(nb >> 1) - 1 + (rr >> 1)];
            v = d * sc[c] + sh[c];
        }
        val[t] = v;
    }
    __syncthreads();

    f32x4* ob = out + (size_t)blk * 32768;   // contiguous 512KB region
    switch (j) {
        case 0: store_region<0>(val, ob, t); break;
        case 1: store_region<1>(val, ob, t); break;
        case 2: store_region<2>(val, ob, t); break;
        default: store_region<3>(val, ob, t); break;
    }
}

extern "C" void kernel_launch(void* const* d_in, const int* in_sizes, int n_in,
                              void* d_out, int out_size, void* d_ws, size_t ws_size,
                              hipStream_t stream) {
    const float* x     = (const float*)d_in[0];
    const float* gamma = (const float*)d_in[1];
    const float* beta  = (const float*)d_in[2];
    f32x4* out = (f32x4*)d_out;
    float* stats = (float*)d_ws;                       // 1024*16 f = 64 KiB
    float* mom   = stats + (size_t)1024 * SSTR;        // 1024*4 f = 16 KiB

    row_stats_kernel<<<1024, 256, 0, stream>>>(x, stats, mom);
    write_all_kernel<<<512, 256, 0, stream>>>(stats, mom, gamma, beta, out);
}